// Round 1
// baseline (87.787 us; speedup 1.0000x reference)
//
#include <hip/hip_runtime.h>
#include <hip/hip_bf16.h>

#define B_SZ 4096
#define N_SZ 8192
#define D_SZ 128

constexpr float TEMP = 0.5f;
constexpr float EPS = 1e-8f;
// exp(dot/TEMP) = exp2(dot * log2(e)/TEMP)
constexpr float EXP_SCALE = 1.4426950408889634f / TEMP;
constexpr float LN2 = 0.6931471805599453f;

typedef short short8 __attribute__((ext_vector_type(8)));   // 8 bf16 (4 VGPRs)
typedef float f32x16 __attribute__((ext_vector_type(16)));  // 32x32 MFMA accumulator

// ---------------------------------------------------------------------------
// Kernel A: normalize rows of p = [z_i; z_j] -> bf16 pn, store clamped norms
// one wave per row; 64 lanes x 2 elems = 128
// ---------------------------------------------------------------------------
__global__ void normalize_kernel(const float* __restrict__ z_i,
                                 const float* __restrict__ z_j,
                                 __hip_bfloat16* __restrict__ pn,
                                 float* __restrict__ norms) {
    int wave = (blockIdx.x * blockDim.x + threadIdx.x) >> 6;  // == row
    int lane = threadIdx.x & 63;
    int row = wave;
    const float* src = (row < B_SZ) ? (z_i + (size_t)row * D_SZ)
                                    : (z_j + (size_t)(row - B_SZ) * D_SZ);
    float2 v = *reinterpret_cast<const float2*>(src + lane * 2);
    float ss = v.x * v.x + v.y * v.y;
#pragma unroll
    for (int m = 32; m >= 1; m >>= 1) ss += __shfl_xor(ss, m, 64);
    float norm = fmaxf(sqrtf(ss), EPS);
    float inv = 1.0f / norm;
    union { unsigned int u; __hip_bfloat16 h[2]; } pack;
    pack.h[0] = __float2bfloat16(v.x * inv);
    pack.h[1] = __float2bfloat16(v.y * inv);
    reinterpret_cast<unsigned int*>(pn + (size_t)row * D_SZ)[lane] = pack.u;
    if (lane == 0) norms[row] = norm;
}

// ---------------------------------------------------------------------------
// Kernel B: sim = pn @ pn^T (bf16 MFMA 32x32x16), row_s[i] += sum_j exp(sim/T)
// (diagonal excluded). Block = 4 waves, each wave owns 32 rows; block covers
// 128 rows x 512 cols. A fragments held in registers for the whole block.
// C/D layout (m74/m101): col = lane&31, row = (reg&3) + 8*(reg>>2) + 4*(lane>>5)
// ---------------------------------------------------------------------------
#define BM 128
#define CN 512

__global__ __launch_bounds__(256, 4)
void simexp_kernel(const __hip_bfloat16* __restrict__ pn_,
                   float* __restrict__ row_s) {
    const short* p = reinterpret_cast<const short*>(pn_);
    int wid = threadIdx.x >> 6;
    int lane = threadIdx.x & 63;
    int half = lane >> 5;   // 0/1
    int lc = lane & 31;     // local col (B) / local row (A)
    int rBase = blockIdx.x * BM + wid * 32;
    int cBase = blockIdx.y * CN;

    // A fragments: lane holds A[rBase+lc][kc*16 + half*8 + e], e in [0,8)
    short8 a[8];
    const short* arow = p + (size_t)(rBase + lc) * D_SZ + half * 8;
#pragma unroll
    for (int kc = 0; kc < 8; ++kc)
        a[kc] = *reinterpret_cast<const short8*>(arow + kc * 16);

    float rowsum[16];
#pragma unroll
    for (int i = 0; i < 16; ++i) rowsum[i] = 0.0f;

    for (int ct = 0; ct < CN / 32; ++ct) {
        int cTile = cBase + ct * 32;
        const short* brow = p + (size_t)(cTile + lc) * D_SZ + half * 8;
        short8 b[8];
#pragma unroll
        for (int kc = 0; kc < 8; ++kc)
            b[kc] = *reinterpret_cast<const short8*>(brow + kc * 16);
        f32x16 acc = {};
#pragma unroll
        for (int kc = 0; kc < 8; ++kc)
            acc = __builtin_amdgcn_mfma_f32_32x32x16_bf16(a[kc], b[kc], acc, 0, 0, 0);

        if (cTile == rBase) {  // wave-uniform: this tile contains the diagonal
#pragma unroll
            for (int r = 0; r < 16; ++r) {
                int lrow = (r & 3) + 8 * (r >> 2) + 4 * half;
                float e = __builtin_amdgcn_exp2f(acc[r] * EXP_SCALE);
                rowsum[r] += (lc == lrow) ? 0.0f : e;
            }
        } else {
#pragma unroll
            for (int r = 0; r < 16; ++r)
                rowsum[r] += __builtin_amdgcn_exp2f(acc[r] * EXP_SCALE);
        }
    }

    // reduce over the 32 columns (lanes sharing `half`)
#pragma unroll
    for (int m = 1; m <= 16; m <<= 1) {
#pragma unroll
        for (int r = 0; r < 16; ++r)
            rowsum[r] += __shfl_xor(rowsum[r], m, 64);
    }
    if (lc == 0) {
#pragma unroll
        for (int r = 0; r < 16; ++r) {
            int grow = rBase + (r & 3) + 8 * (r >> 2) + 4 * half;
            atomicAdd(row_s + grow, rowsum[r]);
        }
    }
}

// ---------------------------------------------------------------------------
// Kernel C1: positives, exact f32. pos_i = dot(z_i[i], z_j[i])/(n_i n_{i+B} T)
// loss contribution: -pos_i / B  (covers both +B and -B diagonals / 2B)
// Block = 256 threads = 16 rows (16-lane group per row), one atomic per block.
// ---------------------------------------------------------------------------
__global__ void pos_kernel(const float* __restrict__ z_i,
                           const float* __restrict__ z_j,
                           const float* __restrict__ norms,
                           float* __restrict__ out) {
    __shared__ float sred[16];
    int tid = threadIdx.x;
    int wid = tid >> 6, lane = tid & 63;
    int g = lane >> 4, gl = lane & 15;
    int row = blockIdx.x * 16 + wid * 4 + g;  // [0, B)
    const float4* a = reinterpret_cast<const float4*>(z_i + (size_t)row * D_SZ) + gl * 2;
    const float4* b = reinterpret_cast<const float4*>(z_j + (size_t)row * D_SZ) + gl * 2;
    float4 a0 = a[0], a1 = a[1], b0 = b[0], b1 = b[1];
    float d = a0.x * b0.x + a0.y * b0.y + a0.z * b0.z + a0.w * b0.w +
              a1.x * b1.x + a1.y * b1.y + a1.z * b1.z + a1.w * b1.w;
#pragma unroll
    for (int m = 1; m <= 8; m <<= 1) d += __shfl_xor(d, m, 64);
    if (gl == 0) {
        float pos = d / (norms[row] * norms[row + B_SZ] * TEMP);
        sred[wid * 4 + g] = -pos / (float)B_SZ;
    }
    __syncthreads();
    if (tid == 0) {
        float s = 0.0f;
#pragma unroll
        for (int i = 0; i < 16; ++i) s += sred[i];
        atomicAdd(out, s);
    }
}

// ---------------------------------------------------------------------------
// Kernel C2: sum of log(row_s)/2B into out. Grid 32 x 256 covers 8192 rows.
// ---------------------------------------------------------------------------
__global__ void lse_kernel(const float* __restrict__ row_s,
                           float* __restrict__ out) {
    __shared__ float sred[4];
    int r = blockIdx.x * blockDim.x + threadIdx.x;
    float v = __logf(row_s[r]) * (1.0f / (2.0f * (float)B_SZ));
#pragma unroll
    for (int m = 32; m >= 1; m >>= 1) v += __shfl_xor(v, m, 64);
    int wid = threadIdx.x >> 6;
    if ((threadIdx.x & 63) == 0) sred[wid] = v;
    __syncthreads();
    if (threadIdx.x == 0)
        atomicAdd(out, sred[0] + sred[1] + sred[2] + sred[3]);
}

// ---------------------------------------------------------------------------
extern "C" void kernel_launch(void* const* d_in, const int* in_sizes, int n_in,
                              void* d_out, int out_size, void* d_ws, size_t ws_size,
                              hipStream_t stream) {
    const float* z_i = (const float*)d_in[0];
    const float* z_j = (const float*)d_in[1];
    float* out = (float*)d_out;
    char* ws = (char*)d_ws;

    __hip_bfloat16* pn = (__hip_bfloat16*)ws;                       // 2 MiB
    float* norms = (float*)(ws + (size_t)N_SZ * D_SZ * 2);          // 32 KiB
    float* row_s = norms + N_SZ;                                    // 32 KiB

    hipMemsetAsync(out, 0, sizeof(float), stream);
    hipMemsetAsync(row_s, 0, N_SZ * sizeof(float), stream);

    normalize_kernel<<<N_SZ / 4, 256, 0, stream>>>(z_i, z_j, pn, norms);

    dim3 grid(N_SZ / BM, N_SZ / CN);
    simexp_kernel<<<grid, 256, 0, stream>>>(pn, row_s);

    pos_kernel<<<B_SZ / 16, 256, 0, stream>>>(z_i, z_j, norms, out);
    lse_kernel<<<N_SZ / 256, 256, 0, stream>>>(row_s, out);
}

// Round 2
// 77.678 us; speedup vs baseline: 1.1301x; 1.1301x over previous
//
#include <hip/hip_runtime.h>
#include <hip/hip_bf16.h>

#define B_SZ 4096
#define N_SZ 8192
#define D_SZ 128

constexpr float TEMP = 0.5f;
constexpr float EPS = 1e-8f;
// exp(dot/TEMP) = exp2(dot * log2(e)/TEMP); sqrt of that scale folded into
// BOTH normalized vectors so acc is directly the exp2 argument.
constexpr float SQS = 1.6986436006556212f;  // sqrt(log2(e)/TEMP)

typedef short short8 __attribute__((ext_vector_type(8)));   // 8 bf16
typedef float f32x16 __attribute__((ext_vector_type(16)));  // 32x32 MFMA acc

// ---------------------------------------------------------------------------
// Kernel A: per wave, handle the row pair (r, r+B). Normalize both into
// bf16 pn (scaled by SQS), zero row_s, compute exact-f32 positive-pair term.
// Block = 4 waves; per-block pos partial -> posbuf (summed later in lse).
// ---------------------------------------------------------------------------
__global__ void norm_pos_kernel(const float* __restrict__ z_i,
                                const float* __restrict__ z_j,
                                unsigned int* __restrict__ pn_u32,
                                float* __restrict__ row_s,
                                float* __restrict__ posbuf) {
    __shared__ float sp[4];
    int wid = threadIdx.x >> 6;
    int lane = threadIdx.x & 63;
    int r = blockIdx.x * 4 + wid;                 // [0, B)
    float2 vi = *reinterpret_cast<const float2*>(z_i + (size_t)r * D_SZ + lane * 2);
    float2 vj = *reinterpret_cast<const float2*>(z_j + (size_t)r * D_SZ + lane * 2);
    float ssi = vi.x * vi.x + vi.y * vi.y;
    float ssj = vj.x * vj.x + vj.y * vj.y;
    float dot = vi.x * vj.x + vi.y * vj.y;
#pragma unroll
    for (int m = 32; m >= 1; m >>= 1) {
        ssi += __shfl_xor(ssi, m, 64);
        ssj += __shfl_xor(ssj, m, 64);
        dot += __shfl_xor(dot, m, 64);
    }
    float ni = fmaxf(sqrtf(ssi), EPS);
    float nj = fmaxf(sqrtf(ssj), EPS);
    float si = SQS / ni, sj = SQS / nj;
    union { unsigned int u; __hip_bfloat16 h[2]; } pk;
    pk.h[0] = __float2bfloat16(vi.x * si);
    pk.h[1] = __float2bfloat16(vi.y * si);
    pn_u32[(size_t)r * (D_SZ / 2) + lane] = pk.u;
    pk.h[0] = __float2bfloat16(vj.x * sj);
    pk.h[1] = __float2bfloat16(vj.y * sj);
    pn_u32[(size_t)(r + B_SZ) * (D_SZ / 2) + lane] = pk.u;
    if (lane == 0) {
        row_s[r] = 0.0f;
        row_s[r + B_SZ] = 0.0f;
        // loss contribution of this positive pair: -dot/(ni*nj*TEMP) / B
        sp[wid] = -dot / (ni * nj * TEMP) / (float)B_SZ;
    }
    __syncthreads();
    if (threadIdx.x == 0)
        posbuf[blockIdx.x] = sp[0] + sp[1] + sp[2] + sp[3];
}

// ---------------------------------------------------------------------------
// Kernel B: E = exp2(pn@pn^T) row sums, exploiting symmetry: process only
// 32x32 tiles with cTile >= rBase; off-diagonal tiles also contribute their
// column sums (= row sums of the mirrored tile). Block = 4 waves x 32 rows,
// CN=256 cols.  C/D layout: col=lane&31, row=(r&3)+8*(r>>2)+4*(lane>>5).
// ---------------------------------------------------------------------------
#define BM 128
#define CN 256

__global__ __launch_bounds__(256, 4)
void simexp_kernel(const short* __restrict__ p, float* __restrict__ row_s) {
    int wid = threadIdx.x >> 6;
    int lane = threadIdx.x & 63;
    int half = lane >> 5;
    int lc = lane & 31;
    int rBase = blockIdx.x * BM + wid * 32;
    int cBase = blockIdx.y * CN;

    int ctStart = (rBase > cBase) ? ((rBase - cBase) >> 5) : 0;
    if (ctStart >= CN / 32) return;  // wave entirely below the diagonal
    int ctDiag = (rBase >= cBase) ? ((rBase - cBase) >> 5) : -1;

    short8 a[8];
    const short* arow = p + (size_t)(rBase + lc) * D_SZ + half * 8;
#pragma unroll
    for (int kc = 0; kc < 8; ++kc)
        a[kc] = *reinterpret_cast<const short8*>(arow + kc * 16);

    float rowsum[16];
#pragma unroll
    for (int i = 0; i < 16; ++i) rowsum[i] = 0.0f;

    for (int ct = ctStart; ct < CN / 32; ++ct) {
        int cTile = cBase + ct * 32;
        const short* brow = p + (size_t)(cTile + lc) * D_SZ + half * 8;
        short8 b[8];
#pragma unroll
        for (int kc = 0; kc < 8; ++kc)
            b[kc] = *reinterpret_cast<const short8*>(brow + kc * 16);
        f32x16 acc = {};
#pragma unroll
        for (int kc = 0; kc < 8; ++kc)
            acc = __builtin_amdgcn_mfma_f32_32x32x16_bf16(a[kc], b[kc], acc, 0, 0, 0);

        if (ct == ctDiag) {  // diagonal tile: mask self-sim, rowsum only
#pragma unroll
            for (int r = 0; r < 16; ++r) {
                int lrow = (r & 3) + 8 * (r >> 2) + 4 * half;
                float e = __builtin_amdgcn_exp2f(acc[r]);
                rowsum[r] += (lc == lrow) ? 0.0f : e;
            }
        } else {             // strictly-upper tile: rowsum + mirrored colsum
            float csum = 0.0f;
#pragma unroll
            for (int r = 0; r < 16; ++r) {
                float e = __builtin_amdgcn_exp2f(acc[r]);
                rowsum[r] += e;
                csum += e;
            }
            csum += __shfl_xor(csum, 32, 64);  // combine the two half-rows
            if (half == 0)
                atomicAdd(row_s + cTile + lc, csum);
        }
    }

    // reduce rowsum over the 32 column-lanes sharing `half`
#pragma unroll
    for (int m = 1; m <= 16; m <<= 1) {
#pragma unroll
        for (int r = 0; r < 16; ++r)
            rowsum[r] += __shfl_xor(rowsum[r], m, 64);
    }
    if (lc == 0) {
#pragma unroll
        for (int r = 0; r < 16; ++r) {
            int grow = rBase + (r & 3) + 8 * (r >> 2) + 4 * half;
            atomicAdd(row_s + grow, rowsum[r]);
        }
    }
}

// ---------------------------------------------------------------------------
// Kernel C: loss += sum(log(row_s))/2B + pos partials. 32 blocks x 256.
// ---------------------------------------------------------------------------
__global__ void lse_kernel(const float* __restrict__ row_s,
                           const float* __restrict__ posbuf,
                           float* __restrict__ out) {
    __shared__ float sred[4];
    int r = blockIdx.x * 256 + threadIdx.x;
    float v = __logf(row_s[r]) * (1.0f / (float)N_SZ);
    if (threadIdx.x < 32) v += posbuf[blockIdx.x * 32 + threadIdx.x];
#pragma unroll
    for (int m = 32; m >= 1; m >>= 1) v += __shfl_xor(v, m, 64);
    int wid = threadIdx.x >> 6;
    if ((threadIdx.x & 63) == 0) sred[wid] = v;
    __syncthreads();
    if (threadIdx.x == 0)
        atomicAdd(out, sred[0] + sred[1] + sred[2] + sred[3]);
}

// ---------------------------------------------------------------------------
extern "C" void kernel_launch(void* const* d_in, const int* in_sizes, int n_in,
                              void* d_out, int out_size, void* d_ws, size_t ws_size,
                              hipStream_t stream) {
    const float* z_i = (const float*)d_in[0];
    const float* z_j = (const float*)d_in[1];
    float* out = (float*)d_out;
    char* ws = (char*)d_ws;

    unsigned int* pn = (unsigned int*)ws;                           // 2 MiB
    float* row_s = (float*)(ws + (size_t)N_SZ * D_SZ * 2);          // 32 KiB
    float* posbuf = row_s + N_SZ;                                   // 4 KiB

    hipMemsetAsync(out, 0, sizeof(float), stream);

    norm_pos_kernel<<<B_SZ / 4, 256, 0, stream>>>(z_i, z_j, pn, row_s, posbuf);

    dim3 grid(N_SZ / BM, N_SZ / CN);
    simexp_kernel<<<grid, 256, 0, stream>>>((const short*)pn, row_s);

    lse_kernel<<<N_SZ / 256, 256, 0, stream>>>(row_s, posbuf, out);
}

// Round 3
// 36.574 us; speedup vs baseline: 2.4002x; 2.1238x over previous
//
#include <hip/hip_runtime.h>
#include <hip/hip_bf16.h>

#define B_SZ 4096
#define N_SZ 8192
#define D_SZ 128

constexpr float TEMP = 0.5f;
constexpr float EPS = 1e-8f;
// exp(dot/TEMP) = exp2(dot * log2(e)/TEMP); sqrt of the scale folded into
// BOTH normalized vectors so acc is directly the exp2 argument.
constexpr float SQS = 1.6986436006556212f;  // sqrt(log2(e)/TEMP)

typedef short short8 __attribute__((ext_vector_type(8)));
typedef float f32x16 __attribute__((ext_vector_type(16)));

// Tiled pn layout (bf16): byte addr of element (row r, col d) =
//   (r>>5)*8192 + (d>>3)*512 + (r&31)*16 + (d&7)*2
// -> MFMA fragment chunk s0 = kc*2+half is 512B contiguous across 32 lanes;
//    a whole 32-row tile is one contiguous 8KB block.

// ---------------------------------------------------------------------------
// Kernel A: per wave, handle row pair (r, r+B). Normalize into tiled-bf16 pn
// (scaled by SQS); exact-f32 positive-pair term -> posbuf[block].
// ---------------------------------------------------------------------------
__global__ void norm_pos_kernel(const float* __restrict__ z_i,
                                const float* __restrict__ z_j,
                                unsigned int* __restrict__ pn_u32,
                                float* __restrict__ posbuf) {
    __shared__ float sp[4];
    int wid = threadIdx.x >> 6;
    int lane = threadIdx.x & 63;
    int r = blockIdx.x * 4 + wid;                 // [0, B)
    float2 vi = *reinterpret_cast<const float2*>(z_i + (size_t)r * D_SZ + lane * 2);
    float2 vj = *reinterpret_cast<const float2*>(z_j + (size_t)r * D_SZ + lane * 2);
    float ssi = vi.x * vi.x + vi.y * vi.y;
    float ssj = vj.x * vj.x + vj.y * vj.y;
    float dot = vi.x * vj.x + vi.y * vj.y;
#pragma unroll
    for (int m = 32; m >= 1; m >>= 1) {
        ssi += __shfl_xor(ssi, m, 64);
        ssj += __shfl_xor(ssj, m, 64);
        dot += __shfl_xor(dot, m, 64);
    }
    float ni = fmaxf(sqrtf(ssi), EPS);
    float nj = fmaxf(sqrtf(ssj), EPS);
    float si = SQS / ni, sj = SQS / nj;
    union { unsigned int u32; __hip_bfloat16 h[2]; } pk;
    // tiled store: lane l holds cols 2l, 2l+1 (one u32)
    int u = ((r >> 5) * 2048) + ((lane >> 2) * 128) + ((r & 31) * 4) + (lane & 3);
    pk.h[0] = __float2bfloat16(vi.x * si);
    pk.h[1] = __float2bfloat16(vi.y * si);
    pn_u32[u] = pk.u32;
    int r2 = r + B_SZ;
    int u2 = ((r2 >> 5) * 2048) + ((lane >> 2) * 128) + ((r2 & 31) * 4) + (lane & 3);
    pk.h[0] = __float2bfloat16(vj.x * sj);
    pk.h[1] = __float2bfloat16(vj.y * sj);
    pn_u32[u2] = pk.u32;
    if (lane == 0)
        sp[wid] = -dot / (ni * nj * TEMP) / (float)B_SZ;
    __syncthreads();
    if (threadIdx.x == 0)
        posbuf[blockIdx.x] = sp[0] + sp[1] + sp[2] + sp[3];
}

// ---------------------------------------------------------------------------
// Kernel B: partial[cs][r] = sum_{j in col strip cs} exp2(sim_rj) (diag
// masked). Block = 4 waves x 64 rows = 256 rows; col strip = 512 cols =
// 16 tiles; B-tile (8KB contiguous) double-buffered in LDS via
// global_load_lds. A fragments in registers (coalesced loads). No atomics.
// C/D layout: col=lane&31, row=(reg&3)+8*(reg>>2)+4*(lane>>5).
// ---------------------------------------------------------------------------
#define CT 16

__global__ __launch_bounds__(256, 2)
void simexp_kernel(const char* __restrict__ p, float* __restrict__ partial) {
    __shared__ char smem[2][8192];
    int wid = threadIdx.x >> 6;
    int lane = threadIdx.x & 63;
    int half = lane >> 5, lc = lane & 31;
    int rt0 = blockIdx.x * 8 + wid * 2;   // wave owns row-tiles rt0, rt0+1
    int rt1 = rt0 + 1;
    int ct0 = blockIdx.y * CT;

    // A fragments: coalesced 1KB loads
    short8 a0[8], a1[8];
    {
        const char* base0 = p + (size_t)rt0 * 8192 + half * 512 + lc * 16;
#pragma unroll
        for (int kc = 0; kc < 8; ++kc) {
            a0[kc] = *reinterpret_cast<const short8*>(base0 + kc * 1024);
            a1[kc] = *reinterpret_cast<const short8*>(base0 + 8192 + kc * 1024);
        }
    }

    float rs0[16], rs1[16];
#pragma unroll
    for (int i = 0; i < 16; ++i) { rs0[i] = 0.0f; rs1[i] = 0.0f; }

    // stage one 8KB col-tile: 2 global_load_lds per wave (linear copy)
    auto stage = [&](int buf, int ct) {
#pragma unroll
        for (int i = 0; i < 2; ++i) {
            int seg = i * 4 + wid;
            const char* g = p + (size_t)ct * 8192 + seg * 1024 + lane * 16;
            __builtin_amdgcn_global_load_lds(
                (const __attribute__((address_space(1))) unsigned int*)g,
                (__attribute__((address_space(3))) unsigned int*)&smem[buf][seg * 1024],
                16, 0, 0);
        }
    };

    stage(0, ct0);
    __syncthreads();

    for (int t = 0; t < CT; ++t) {
        if (t + 1 < CT) stage((t + 1) & 1, ct0 + t + 1);
        const char* bb = &smem[t & 1][0] + half * 512 + lc * 16;
        short8 b[8];
#pragma unroll
        for (int kc = 0; kc < 8; ++kc)
            b[kc] = *reinterpret_cast<const short8*>(bb + kc * 1024);
        f32x16 acc0 = {}, acc1 = {};
#pragma unroll
        for (int kc = 0; kc < 8; ++kc) {
            acc0 = __builtin_amdgcn_mfma_f32_32x32x16_bf16(a0[kc], b[kc], acc0, 0, 0, 0);
            acc1 = __builtin_amdgcn_mfma_f32_32x32x16_bf16(a1[kc], b[kc], acc1, 0, 0, 0);
        }
        int ct_g = ct0 + t;
        bool d0 = (ct_g == rt0), d1 = (ct_g == rt1);
        if (d0 | d1) {  // wave-uniform: tile contains a diagonal block
#pragma unroll
            for (int r = 0; r < 16; ++r) {
                int lrow = (r & 3) + 8 * (r >> 2) + 4 * half;
                float e0 = __builtin_amdgcn_exp2f(acc0[r]);
                float e1 = __builtin_amdgcn_exp2f(acc1[r]);
                rs0[r] += (d0 && lc == lrow) ? 0.0f : e0;
                rs1[r] += (d1 && lc == lrow) ? 0.0f : e1;
            }
        } else {
#pragma unroll
            for (int r = 0; r < 16; ++r) {
                rs0[r] += __builtin_amdgcn_exp2f(acc0[r]);
                rs1[r] += __builtin_amdgcn_exp2f(acc1[r]);
            }
        }
        __syncthreads();
    }

    // reduce across the 32 column lanes
#pragma unroll
    for (int m = 1; m <= 16; m <<= 1) {
#pragma unroll
        for (int r = 0; r < 16; ++r) {
            rs0[r] += __shfl_xor(rs0[r], m, 64);
            rs1[r] += __shfl_xor(rs1[r], m, 64);
        }
    }
    if (lc == 0) {
        float* dst = partial + (size_t)blockIdx.y * N_SZ;
#pragma unroll
        for (int r = 0; r < 16; ++r) {
            int lrow = (r & 3) + 8 * (r >> 2) + 4 * half;
            dst[rt0 * 32 + lrow] = rs0[r];
            dst[rt1 * 32 + lrow] = rs1[r];
        }
    }
}

// ---------------------------------------------------------------------------
// Kernel C: loss = sum(log(rowsum))/2B + pos partials. 32 blocks x 256.
// ---------------------------------------------------------------------------
__global__ void lse_kernel(const float* __restrict__ partial,
                           const float* __restrict__ posbuf,
                           float* __restrict__ out) {
    __shared__ float sred[4];
    int r = blockIdx.x * 256 + threadIdx.x;
    float s = 0.0f;
#pragma unroll
    for (int c = 0; c < CT; ++c) s += partial[(size_t)c * N_SZ + r];
    float v = __logf(s) * (1.0f / (float)N_SZ);
    if (threadIdx.x < 32) v += posbuf[blockIdx.x * 32 + threadIdx.x];
#pragma unroll
    for (int m = 32; m >= 1; m >>= 1) v += __shfl_xor(v, m, 64);
    int wid = threadIdx.x >> 6;
    if ((threadIdx.x & 63) == 0) sred[wid] = v;
    __syncthreads();
    if (threadIdx.x == 0)
        atomicAdd(out, sred[0] + sred[1] + sred[2] + sred[3]);
}

// ---------------------------------------------------------------------------
extern "C" void kernel_launch(void* const* d_in, const int* in_sizes, int n_in,
                              void* d_out, int out_size, void* d_ws, size_t ws_size,
                              hipStream_t stream) {
    const float* z_i = (const float*)d_in[0];
    const float* z_j = (const float*)d_in[1];
    float* out = (float*)d_out;
    char* ws = (char*)d_ws;

    unsigned int* pn = (unsigned int*)ws;                            // 2 MiB
    float* partial = (float*)(ws + (size_t)N_SZ * D_SZ * 2);         // 512 KiB
    float* posbuf = partial + (size_t)CT * N_SZ;                     // 4 KiB

    hipMemsetAsync(out, 0, sizeof(float), stream);

    norm_pos_kernel<<<B_SZ / 4, 256, 0, stream>>>(z_i, z_j, pn, posbuf);

    dim3 grid(N_SZ / 256, N_SZ / 512);  // 32 x 16
    simexp_kernel<<<grid, 256, 0, stream>>>((const char*)pn, partial);

    lse_kernel<<<N_SZ / 256, 256, 0, stream>>>(partial, posbuf, out);
}